// Round 6
// baseline (249.286 us; speedup 1.0000x reference)
//
#include <hip/hip_runtime.h>

#define N_NODES   50000
#define N_EDGES   800000
#define IN_DIM    89
#define KP1       96      // IN_DIM padded to multiple of 32
#define HID       128
#define N_CLASSES 64
#define N_GRAPHS  64

typedef __attribute__((ext_vector_type(8))) short bf16x8;
typedef __attribute__((ext_vector_type(4))) float f32x4;

__device__ __forceinline__ unsigned short f2bf(float x) {
    union { float f; unsigned u; } v; v.f = x;
    unsigned r = v.u + 0x7FFF + ((v.u >> 16) & 1);   // RTNE
    return (unsigned short)(r >> 16);
}
__device__ __forceinline__ float bf2f(unsigned short x) {
    union { unsigned u; float f; } v; v.u = ((unsigned)x) << 16;
    return v.f;
}

// ---------------------------------------------------------------------------
// Fused prep: conv_nf | rowptr | wt1/wt2/wt3 transpose+bf16, branched by block.
// ---------------------------------------------------------------------------
#define NB_CONV 18750                      // 50000*96/256
#define NB_ROW  196                        // ceil(50001/256)
#define NB_WT   176                        // ceil((128*96+2*128*128)/256)

__global__ void prep_kernel(const float* __restrict__ nf,
                            const int* __restrict__ dst,
                            const int* __restrict__ gid,
                            const float* __restrict__ W1,
                            const float* __restrict__ W2,
                            const float* __restrict__ W3,
                            unsigned short* __restrict__ nfb,
                            int* __restrict__ node_ptr,
                            int* __restrict__ graph_ptr,
                            unsigned short* __restrict__ wt1,
                            unsigned short* __restrict__ wt2,
                            unsigned short* __restrict__ wt3) {
    const int b = blockIdx.x;
    if (b < NB_CONV) {
        const int i = b * 256 + threadIdx.x;           // < 4.8M exactly
        const int row = i / KP1, k = i - row * KP1;
        nfb[i] = (k < IN_DIM) ? f2bf(nf[(size_t)row * IN_DIM + k]) : (unsigned short)0;
    } else if (b < NB_CONV + NB_ROW) {
        const int i = (b - NB_CONV) * 256 + threadIdx.x;
        if (i <= N_NODES) {
            int lo = 0, hi = N_EDGES;
            while (lo < hi) { int mid = (lo + hi) >> 1; if (dst[mid] < i) lo = mid + 1; else hi = mid; }
            node_ptr[i] = lo;
        }
        if (i <= N_GRAPHS) {
            int lo = 0, hi = N_NODES;
            while (lo < hi) { int mid = (lo + hi) >> 1; if (gid[mid] < i) lo = mid + 1; else hi = mid; }
            graph_ptr[i] = lo;
        }
    } else {
        int idx = (b - NB_CONV - NB_ROW) * 256 + threadIdx.x;
        if (idx < HID * KP1) {
            const int col = idx / KP1, k = idx - col * KP1;
            wt1[idx] = (k < IN_DIM) ? f2bf(W1[(size_t)k * HID + col]) : (unsigned short)0;
        } else if ((idx -= HID * KP1) < HID * HID) {
            const int col = idx / HID, k = idx - col * HID;
            wt2[idx] = f2bf(W2[(size_t)k * HID + col]);
        } else if ((idx -= HID * HID) < HID * HID) {
            const int col = idx / HID, k = idx - col * HID;
            wt3[idx] = f2bf(W3[(size_t)k * HID + col]);
        }
    }
}

// ---------------------------------------------------------------------------
// MFMA GEMM (layer 1 only): Y[M x 128](bf16) = Xb[M x KPAD](bf16) @ WT^T.
// Block = 4 waves; wave = 16 rows x 128 cols. No LDS.
// ---------------------------------------------------------------------------
template <int KPAD>
__global__ __launch_bounds__(256) void mfma_gemm_kernel(
        const unsigned short* __restrict__ Xb,
        const unsigned short* __restrict__ WT,
        unsigned short* __restrict__ Y, int M) {
    const int wave = threadIdx.x >> 6;
    const int lane = threadIdx.x & 63;
    const int r    = lane & 15;
    const int kg   = lane >> 4;

    const int row  = blockIdx.x * 64 + wave * 16 + r;
    const int rowc = (row < M) ? row : (M - 1);

    f32x4 acc[8];
#pragma unroll
    for (int i = 0; i < 8; ++i) acc[i] = (f32x4){0.f, 0.f, 0.f, 0.f};

    const unsigned short* xrow = Xb + (size_t)rowc * KPAD + kg * 8;

#pragma unroll
    for (int k0 = 0; k0 < KPAD; k0 += 32) {
        const bf16x8 a = *reinterpret_cast<const bf16x8*>(xrow + k0);
#pragma unroll
        for (int nf = 0; nf < 8; ++nf) {
            const bf16x8 b = *reinterpret_cast<const bf16x8*>(
                WT + (size_t)(nf * 16 + r) * KPAD + kg * 8 + k0);
            acc[nf] = __builtin_amdgcn_mfma_f32_16x16x32_bf16(a, b, acc[nf], 0, 0, 0);
        }
    }

    const int orow0 = blockIdx.x * 64 + wave * 16 + kg * 4;
#pragma unroll
    for (int nf = 0; nf < 8; ++nf)
#pragma unroll
        for (int q = 0; q < 4; ++q) {
            const int orow = orow0 + q;
            if (orow < M) Y[(size_t)orow * HID + nf * 16 + r] = f2bf(acc[nf][q]);
        }
}

// ---------------------------------------------------------------------------
// FUSED agg + GEMM:  h = relu(mean-agg(Pin) + bias);  Pout = h @ W (via WT).
// Block = 4 waves x 64 nodes. Wave w aggregates its 16 nodes into a private
// LDS tile (stride 136 shorts -> 2-way banks, free), then runs the 16x128
// MFMA GEMM reading A from LDS. Wave-synchronous: no __syncthreads needed.
// ---------------------------------------------------------------------------
__global__ __launch_bounds__(256) void fused_agg_gemm_kernel(
        const unsigned short* __restrict__ Pin,
        const int* __restrict__ src,
        const int* __restrict__ node_ptr,
        const float* __restrict__ bias,
        const unsigned short* __restrict__ WT,
        unsigned short* __restrict__ Pout, int M) {
    __shared__ unsigned short hs[4][16][136];   // per-wave 16 x 128 (+8 pad)

    const int wave = threadIdx.x >> 6;
    const int lane = threadIdx.x & 63;
    const int q    = lane >> 4;                 // edge sub-slot 0..3
    const int g    = lane & 15;                 // dim group [8g, 8g+8)

    // ---- phase 1: aggregate 16 nodes into LDS ----
    const float4 b0 = *reinterpret_cast<const float4*>(bias + g * 8);
    const float4 b1 = *reinterpret_cast<const float4*>(bias + g * 8 + 4);

    for (int i = 0; i < 16; ++i) {
        const int v = blockIdx.x * 64 + wave * 16 + i;
        if (v < M) {
            const int lo = node_ptr[v];
            const int hi = node_ptr[v + 1];
            const float inv = 1.0f / (float)max(hi - lo, 1);

            float acc[8];
#pragma unroll
            for (int j = 0; j < 8; ++j) acc[j] = 0.f;

            int e = lo + q;
            for (; e + 4 < hi; e += 8) {        // 2x unroll for MLP
                const int u0 = src[e];
                const int u1 = src[e + 4];
                const bf16x8 r0 = *reinterpret_cast<const bf16x8*>(Pin + (size_t)u0 * HID + g * 8);
                const bf16x8 r1 = *reinterpret_cast<const bf16x8*>(Pin + (size_t)u1 * HID + g * 8);
#pragma unroll
                for (int j = 0; j < 8; ++j)
                    acc[j] += bf2f((unsigned short)r0[j]) + bf2f((unsigned short)r1[j]);
            }
            if (e < hi) {
                const int u = src[e];
                const bf16x8 r = *reinterpret_cast<const bf16x8*>(Pin + (size_t)u * HID + g * 8);
#pragma unroll
                for (int j = 0; j < 8; ++j) acc[j] += bf2f((unsigned short)r[j]);
            }
#pragma unroll
            for (int j = 0; j < 8; ++j) {
                acc[j] += __shfl_xor(acc[j], 16);
                acc[j] += __shfl_xor(acc[j], 32);
            }
            if (q == 0) {
                bf16x8 ob;
                ob[0] = (short)f2bf(fmaxf(acc[0] * inv + b0.x, 0.f));
                ob[1] = (short)f2bf(fmaxf(acc[1] * inv + b0.y, 0.f));
                ob[2] = (short)f2bf(fmaxf(acc[2] * inv + b0.z, 0.f));
                ob[3] = (short)f2bf(fmaxf(acc[3] * inv + b0.w, 0.f));
                ob[4] = (short)f2bf(fmaxf(acc[4] * inv + b1.x, 0.f));
                ob[5] = (short)f2bf(fmaxf(acc[5] * inv + b1.y, 0.f));
                ob[6] = (short)f2bf(fmaxf(acc[6] * inv + b1.z, 0.f));
                ob[7] = (short)f2bf(fmaxf(acc[7] * inv + b1.w, 0.f));
                *reinterpret_cast<bf16x8*>(&hs[wave][i][g * 8]) = ob;
            }
        } else if (q == 0) {
            bf16x8 z = (bf16x8){0,0,0,0,0,0,0,0};
            *reinterpret_cast<bf16x8*>(&hs[wave][i][g * 8]) = z;
        }
    }

    // ---- phase 2: GEMM 16x128 = hs[wave] @ W ----
    const int r  = lane & 15;
    const int kg = lane >> 4;

    f32x4 acc2[8];
#pragma unroll
    for (int i = 0; i < 8; ++i) acc2[i] = (f32x4){0.f, 0.f, 0.f, 0.f};

#pragma unroll
    for (int k0 = 0; k0 < HID; k0 += 32) {
        const bf16x8 a = *reinterpret_cast<const bf16x8*>(&hs[wave][r][kg * 8 + k0]);
#pragma unroll
        for (int nf = 0; nf < 8; ++nf) {
            const bf16x8 b = *reinterpret_cast<const bf16x8*>(
                WT + (size_t)(nf * 16 + r) * HID + kg * 8 + k0);
            acc2[nf] = __builtin_amdgcn_mfma_f32_16x16x32_bf16(a, b, acc2[nf], 0, 0, 0);
        }
    }

    const int orow0 = blockIdx.x * 64 + wave * 16 + kg * 4;
#pragma unroll
    for (int nf = 0; nf < 8; ++nf)
#pragma unroll
        for (int p = 0; p < 4; ++p) {
            const int orow = orow0 + p;
            if (orow < M) Pout[(size_t)orow * HID + nf * 16 + r] = f2bf(acc2[nf][p]);
        }
}

// ---------------------------------------------------------------------------
// Final aggregation (layer 3): fp32 output for pooling.
// ---------------------------------------------------------------------------
__global__ void agg128_f32_kernel(const unsigned short* __restrict__ Pb,
                                  const int* __restrict__ src,
                                  const int* __restrict__ node_ptr,
                                  const float* __restrict__ bias,
                                  float* __restrict__ out) {
    const int wave = threadIdx.x >> 6;
    const int lane = threadIdx.x & 63;
    const int v    = blockIdx.x * 4 + wave;
    if (v >= N_NODES) return;

    const int lo = node_ptr[v];
    const int hi = node_ptr[v + 1];
    const float inv = 1.0f / (float)max(hi - lo, 1);

    const int q = lane >> 4;
    const int g = lane & 15;

    float acc[8];
#pragma unroll
    for (int j = 0; j < 8; ++j) acc[j] = 0.f;

    int e = lo + q;
    for (; e + 4 < hi; e += 8) {
        const int u0 = src[e];
        const int u1 = src[e + 4];
        const bf16x8 r0 = *reinterpret_cast<const bf16x8*>(Pb + (size_t)u0 * HID + g * 8);
        const bf16x8 r1 = *reinterpret_cast<const bf16x8*>(Pb + (size_t)u1 * HID + g * 8);
#pragma unroll
        for (int j = 0; j < 8; ++j)
            acc[j] += bf2f((unsigned short)r0[j]) + bf2f((unsigned short)r1[j]);
    }
    if (e < hi) {
        const int u = src[e];
        const bf16x8 r = *reinterpret_cast<const bf16x8*>(Pb + (size_t)u * HID + g * 8);
#pragma unroll
        for (int j = 0; j < 8; ++j) acc[j] += bf2f((unsigned short)r[j]);
    }
#pragma unroll
    for (int j = 0; j < 8; ++j) {
        acc[j] += __shfl_xor(acc[j], 16);
        acc[j] += __shfl_xor(acc[j], 32);
    }

    if (q == 0) {
        const float4 b0 = *reinterpret_cast<const float4*>(bias + g * 8);
        const float4 b1 = *reinterpret_cast<const float4*>(bias + g * 8 + 4);
        float4 a = make_float4(fmaxf(acc[0] * inv + b0.x, 0.f), fmaxf(acc[1] * inv + b0.y, 0.f),
                               fmaxf(acc[2] * inv + b0.z, 0.f), fmaxf(acc[3] * inv + b0.w, 0.f));
        float4 b = make_float4(fmaxf(acc[4] * inv + b1.x, 0.f), fmaxf(acc[5] * inv + b1.y, 0.f),
                               fmaxf(acc[6] * inv + b1.z, 0.f), fmaxf(acc[7] * inv + b1.w, 0.f));
        *reinterpret_cast<float4*>(out + (size_t)v * HID + g * 8)     = a;
        *reinterpret_cast<float4*>(out + (size_t)v * HID + g * 8 + 4) = b;
    }
}

// ---------------------------------------------------------------------------
// Fused pool + cls1 + cls2: one block per graph (row-local classifier).
// ---------------------------------------------------------------------------
__global__ void poolcls_kernel(const float* __restrict__ h3,
                               const int* __restrict__ graph_ptr,
                               const float* __restrict__ Wc1,
                               const float* __restrict__ bc1,
                               const float* __restrict__ Wc2,
                               const float* __restrict__ bc2,
                               float* __restrict__ out) {
    const int g = blockIdx.x;                   // 64
    const int j = threadIdx.x;                  // 128
    const int lo = graph_ptr[g];
    const int hi = graph_ptr[g + 1];
    const float inv = 1.0f / (float)max(hi - lo, 1);

    float acc = 0.f;
    int r = lo;
    for (; r + 4 <= hi; r += 4)
        acc += h3[(size_t)r * HID + j] + h3[(size_t)(r + 1) * HID + j]
             + h3[(size_t)(r + 2) * HID + j] + h3[(size_t)(r + 3) * HID + j];
    for (; r < hi; ++r) acc += h3[(size_t)r * HID + j];

    __shared__ float row[HID];
    __shared__ float trow[HID];
    row[j] = acc * inv;
    __syncthreads();

    float a1 = bc1[j];
#pragma unroll 4
    for (int k = 0; k < HID; ++k) a1 = fmaf(row[k], Wc1[k * HID + j], a1);
    trow[j] = fmaxf(a1, 0.f);
    __syncthreads();

    if (j < N_CLASSES) {
        float a2 = bc2[j];
#pragma unroll 4
        for (int k = 0; k < HID; ++k) a2 = fmaf(trow[k], Wc2[k * N_CLASSES + j], a2);
        out[g * N_CLASSES + j] = a2;
    }
}

// ---------------------------------------------------------------------------
extern "C" void kernel_launch(void* const* d_in, const int* in_sizes, int n_in,
                              void* d_out, int out_size, void* d_ws, size_t ws_size,
                              hipStream_t stream) {
    const float* nf   = (const float*)d_in[0];
    const int*   src  = (const int*)  d_in[1];
    const int*   dst  = (const int*)  d_in[2];
    const int*   gid  = (const int*)  d_in[3];
    const float* W1  = (const float*)d_in[5];
    const float* b1  = (const float*)d_in[6];
    const float* W2  = (const float*)d_in[7];
    const float* b2  = (const float*)d_in[8];
    const float* W3  = (const float*)d_in[9];
    const float* b3  = (const float*)d_in[10];
    const float* Wc1 = (const float*)d_in[11];
    const float* bc1 = (const float*)d_in[12];
    const float* Wc2 = (const float*)d_in[13];
    const float* bc2 = (const float*)d_in[14];
    float* out = (float*)d_out;

    char* ws = (char*)d_ws;
    size_t off = 0;
    auto alloc = [&](size_t bytes) { void* p = ws + off; off = (off + bytes + 255) & ~(size_t)255; return p; };
    int*   node_ptr  = (int*)  alloc((N_NODES + 1) * sizeof(int));
    int*   graph_ptr = (int*)  alloc((N_GRAPHS + 1) * sizeof(int));
    // region A: nfb (bf16 M x 96) dead after gemm1; reused for h3 (fp32 M x 128)
    char*  regionA   = (char*) alloc((size_t)N_NODES * HID * sizeof(float));
    unsigned short* nfb = (unsigned short*)regionA;
    float*          h3  = (float*)regionA;
    unsigned short* PbA = (unsigned short*)alloc((size_t)N_NODES * HID * sizeof(unsigned short));
    unsigned short* PbB = (unsigned short*)alloc((size_t)N_NODES * HID * sizeof(unsigned short));
    unsigned short* wt1 = (unsigned short*)alloc((size_t)HID * KP1 * sizeof(unsigned short));
    unsigned short* wt2 = (unsigned short*)alloc((size_t)HID * HID * sizeof(unsigned short));
    unsigned short* wt3 = (unsigned short*)alloc((size_t)HID * HID * sizeof(unsigned short));
    (void)ws_size;

    const int GEMM_GRID = (N_NODES + 63) / 64;   // 782
    const int AGG_GRID  = (N_NODES + 3) / 4;

    // 1. fused prep
    prep_kernel<<<NB_CONV + NB_ROW + NB_WT, 256, 0, stream>>>(
        nf, dst, gid, W1, W2, W3, nfb, node_ptr, graph_ptr, wt1, wt2, wt3);

    // 2. P1 = nfb @ W1
    mfma_gemm_kernel<KP1><<<GEMM_GRID, 256, 0, stream>>>(nfb, wt1, PbA, N_NODES);

    // 3. h1 = relu(agg(P1)+b1); P2 = h1 @ W2
    fused_agg_gemm_kernel<<<GEMM_GRID, 256, 0, stream>>>(PbA, src, node_ptr, b1, wt2, PbB, N_NODES);

    // 4. h2 = relu(agg(P2)+b2); P3 = h2 @ W3
    fused_agg_gemm_kernel<<<GEMM_GRID, 256, 0, stream>>>(PbB, src, node_ptr, b2, wt3, PbA, N_NODES);

    // 5. h3 = relu(agg(P3)+b3)  (fp32)
    agg128_f32_kernel<<<AGG_GRID, 256, 0, stream>>>(PbA, src, node_ptr, b3, h3);

    // 6. pool + classifier
    poolcls_kernel<<<N_GRAPHS, HID, 0, stream>>>(h3, graph_ptr, Wc1, bc1, Wc2, bc2, out);
}

// Round 7
// 216.075 us; speedup vs baseline: 1.1537x; 1.1537x over previous
//
#include <hip/hip_runtime.h>

#define N_NODES   50000
#define N_EDGES   800000
#define IN_DIM    89
#define KP1       96      // IN_DIM padded to multiple of 32
#define HID       128
#define N_CLASSES 64
#define N_GRAPHS  64
#define PSPLIT    16      // pool partial splits per graph

typedef __attribute__((ext_vector_type(8))) short bf16x8;
typedef __attribute__((ext_vector_type(4))) float f32x4;

__device__ __forceinline__ unsigned short f2bf(float x) {
    union { float f; unsigned u; } v; v.f = x;
    unsigned r = v.u + 0x7FFF + ((v.u >> 16) & 1);   // RTNE
    return (unsigned short)(r >> 16);
}
__device__ __forceinline__ float bf2f(unsigned short x) {
    union { unsigned u; float f; } v; v.u = ((unsigned)x) << 16;
    return v.f;
}

// ---------------------------------------------------------------------------
// Fused prep: conv_nf | rowptr | wt1/wt2/wt3 transpose+bf16, branched by block.
// ---------------------------------------------------------------------------
#define NB_CONV 18750                      // 50000*96/256
#define NB_ROW  196                        // ceil(50001/256)
#define NB_WT   176                        // ceil((128*96+2*128*128)/256)

__global__ void prep_kernel(const float* __restrict__ nf,
                            const int* __restrict__ dst,
                            const int* __restrict__ gid,
                            const float* __restrict__ W1,
                            const float* __restrict__ W2,
                            const float* __restrict__ W3,
                            unsigned short* __restrict__ nfb,
                            int* __restrict__ node_ptr,
                            int* __restrict__ graph_ptr,
                            unsigned short* __restrict__ wt1,
                            unsigned short* __restrict__ wt2,
                            unsigned short* __restrict__ wt3) {
    const int b = blockIdx.x;
    if (b < NB_CONV) {
        const int i = b * 256 + threadIdx.x;           // < 4.8M exactly
        const int row = i / KP1, k = i - row * KP1;
        nfb[i] = (k < IN_DIM) ? f2bf(nf[(size_t)row * IN_DIM + k]) : (unsigned short)0;
    } else if (b < NB_CONV + NB_ROW) {
        const int i = (b - NB_CONV) * 256 + threadIdx.x;
        if (i <= N_NODES) {
            int lo = 0, hi = N_EDGES;
            while (lo < hi) { int mid = (lo + hi) >> 1; if (dst[mid] < i) lo = mid + 1; else hi = mid; }
            node_ptr[i] = lo;
        }
        if (i <= N_GRAPHS) {
            int lo = 0, hi = N_NODES;
            while (lo < hi) { int mid = (lo + hi) >> 1; if (gid[mid] < i) lo = mid + 1; else hi = mid; }
            graph_ptr[i] = lo;
        }
    } else {
        int idx = (b - NB_CONV - NB_ROW) * 256 + threadIdx.x;
        if (idx < HID * KP1) {
            const int col = idx / KP1, k = idx - col * KP1;
            wt1[idx] = (k < IN_DIM) ? f2bf(W1[(size_t)k * HID + col]) : (unsigned short)0;
        } else if ((idx -= HID * KP1) < HID * HID) {
            const int col = idx / HID, k = idx - col * HID;
            wt2[idx] = f2bf(W2[(size_t)k * HID + col]);
        } else if ((idx -= HID * HID) < HID * HID) {
            const int col = idx / HID, k = idx - col * HID;
            wt3[idx] = f2bf(W3[(size_t)k * HID + col]);
        }
    }
}

// ---------------------------------------------------------------------------
// MFMA GEMM (layer 1 only): Y[M x 128](bf16) = Xb[M x KPAD](bf16) @ WT^T.
// Block = 4 waves; wave = 16 rows x 128 cols. No LDS.
// ---------------------------------------------------------------------------
template <int KPAD>
__global__ __launch_bounds__(256) void mfma_gemm_kernel(
        const unsigned short* __restrict__ Xb,
        const unsigned short* __restrict__ WT,
        unsigned short* __restrict__ Y, int M) {
    const int wave = threadIdx.x >> 6;
    const int lane = threadIdx.x & 63;
    const int r    = lane & 15;
    const int kg   = lane >> 4;

    const int row  = blockIdx.x * 64 + wave * 16 + r;
    const int rowc = (row < M) ? row : (M - 1);

    f32x4 acc[8];
#pragma unroll
    for (int i = 0; i < 8; ++i) acc[i] = (f32x4){0.f, 0.f, 0.f, 0.f};

    const unsigned short* xrow = Xb + (size_t)rowc * KPAD + kg * 8;

#pragma unroll
    for (int k0 = 0; k0 < KPAD; k0 += 32) {
        const bf16x8 a = *reinterpret_cast<const bf16x8*>(xrow + k0);
#pragma unroll
        for (int nf = 0; nf < 8; ++nf) {
            const bf16x8 b = *reinterpret_cast<const bf16x8*>(
                WT + (size_t)(nf * 16 + r) * KPAD + kg * 8 + k0);
            acc[nf] = __builtin_amdgcn_mfma_f32_16x16x32_bf16(a, b, acc[nf], 0, 0, 0);
        }
    }

    const int orow0 = blockIdx.x * 64 + wave * 16 + kg * 4;
#pragma unroll
    for (int nf = 0; nf < 8; ++nf)
#pragma unroll
        for (int q = 0; q < 4; ++q) {
            const int orow = orow0 + q;
            if (orow < M) Y[(size_t)orow * HID + nf * 16 + r] = f2bf(acc[nf][q]);
        }
}

// ---------------------------------------------------------------------------
// FUSED agg + GEMM:  h = relu(mean-agg(Pin) + bias);  Pout = h @ W (via WT).
// Block = 4 waves x 64 nodes. Wave-private LDS tile; wave-synchronous.
// ---------------------------------------------------------------------------
__global__ __launch_bounds__(256) void fused_agg_gemm_kernel(
        const unsigned short* __restrict__ Pin,
        const int* __restrict__ src,
        const int* __restrict__ node_ptr,
        const float* __restrict__ bias,
        const unsigned short* __restrict__ WT,
        unsigned short* __restrict__ Pout, int M) {
    __shared__ unsigned short hs[4][16][136];   // per-wave 16 x 128 (+8 pad)

    const int wave = threadIdx.x >> 6;
    const int lane = threadIdx.x & 63;
    const int q    = lane >> 4;                 // edge sub-slot 0..3
    const int g    = lane & 15;                 // dim group [8g, 8g+8)

    // ---- phase 1: aggregate 16 nodes into LDS ----
    const float4 b0 = *reinterpret_cast<const float4*>(bias + g * 8);
    const float4 b1 = *reinterpret_cast<const float4*>(bias + g * 8 + 4);

    for (int i = 0; i < 16; ++i) {
        const int v = blockIdx.x * 64 + wave * 16 + i;
        if (v < M) {
            const int lo = node_ptr[v];
            const int hi = node_ptr[v + 1];
            const float inv = 1.0f / (float)max(hi - lo, 1);

            float acc[8];
#pragma unroll
            for (int j = 0; j < 8; ++j) acc[j] = 0.f;

            int e = lo + q;
            for (; e + 4 < hi; e += 8) {        // 2x unroll for MLP
                const int u0 = src[e];
                const int u1 = src[e + 4];
                const bf16x8 r0 = *reinterpret_cast<const bf16x8*>(Pin + (size_t)u0 * HID + g * 8);
                const bf16x8 r1 = *reinterpret_cast<const bf16x8*>(Pin + (size_t)u1 * HID + g * 8);
#pragma unroll
                for (int j = 0; j < 8; ++j)
                    acc[j] += bf2f((unsigned short)r0[j]) + bf2f((unsigned short)r1[j]);
            }
            if (e < hi) {
                const int u = src[e];
                const bf16x8 r = *reinterpret_cast<const bf16x8*>(Pin + (size_t)u * HID + g * 8);
#pragma unroll
                for (int j = 0; j < 8; ++j) acc[j] += bf2f((unsigned short)r[j]);
            }
#pragma unroll
            for (int j = 0; j < 8; ++j) {
                acc[j] += __shfl_xor(acc[j], 16);
                acc[j] += __shfl_xor(acc[j], 32);
            }
            if (q == 0) {
                bf16x8 ob;
                ob[0] = (short)f2bf(fmaxf(acc[0] * inv + b0.x, 0.f));
                ob[1] = (short)f2bf(fmaxf(acc[1] * inv + b0.y, 0.f));
                ob[2] = (short)f2bf(fmaxf(acc[2] * inv + b0.z, 0.f));
                ob[3] = (short)f2bf(fmaxf(acc[3] * inv + b0.w, 0.f));
                ob[4] = (short)f2bf(fmaxf(acc[4] * inv + b1.x, 0.f));
                ob[5] = (short)f2bf(fmaxf(acc[5] * inv + b1.y, 0.f));
                ob[6] = (short)f2bf(fmaxf(acc[6] * inv + b1.z, 0.f));
                ob[7] = (short)f2bf(fmaxf(acc[7] * inv + b1.w, 0.f));
                *reinterpret_cast<bf16x8*>(&hs[wave][i][g * 8]) = ob;
            }
        } else if (q == 0) {
            bf16x8 z = (bf16x8){0,0,0,0,0,0,0,0};
            *reinterpret_cast<bf16x8*>(&hs[wave][i][g * 8]) = z;
        }
    }

    // ---- phase 2: GEMM 16x128 = hs[wave] @ W ----
    const int r  = lane & 15;
    const int kg = lane >> 4;

    f32x4 acc2[8];
#pragma unroll
    for (int i = 0; i < 8; ++i) acc2[i] = (f32x4){0.f, 0.f, 0.f, 0.f};

#pragma unroll
    for (int k0 = 0; k0 < HID; k0 += 32) {
        const bf16x8 a = *reinterpret_cast<const bf16x8*>(&hs[wave][r][kg * 8 + k0]);
#pragma unroll
        for (int nf = 0; nf < 8; ++nf) {
            const bf16x8 b = *reinterpret_cast<const bf16x8*>(
                WT + (size_t)(nf * 16 + r) * HID + kg * 8 + k0);
            acc2[nf] = __builtin_amdgcn_mfma_f32_16x16x32_bf16(a, b, acc2[nf], 0, 0, 0);
        }
    }

    const int orow0 = blockIdx.x * 64 + wave * 16 + kg * 4;
#pragma unroll
    for (int nf = 0; nf < 8; ++nf)
#pragma unroll
        for (int p = 0; p < 4; ++p) {
            const int orow = orow0 + p;
            if (orow < M) Pout[(size_t)orow * HID + nf * 16 + r] = f2bf(acc2[nf][p]);
        }
}

// ---------------------------------------------------------------------------
// Final aggregation (layer 3): fp32 output for pooling.
// ---------------------------------------------------------------------------
__global__ void agg128_f32_kernel(const unsigned short* __restrict__ Pb,
                                  const int* __restrict__ src,
                                  const int* __restrict__ node_ptr,
                                  const float* __restrict__ bias,
                                  float* __restrict__ out) {
    const int wave = threadIdx.x >> 6;
    const int lane = threadIdx.x & 63;
    const int v    = blockIdx.x * 4 + wave;
    if (v >= N_NODES) return;

    const int lo = node_ptr[v];
    const int hi = node_ptr[v + 1];
    const float inv = 1.0f / (float)max(hi - lo, 1);

    const int q = lane >> 4;
    const int g = lane & 15;

    float acc[8];
#pragma unroll
    for (int j = 0; j < 8; ++j) acc[j] = 0.f;

    int e = lo + q;
    for (; e + 4 < hi; e += 8) {
        const int u0 = src[e];
        const int u1 = src[e + 4];
        const bf16x8 r0 = *reinterpret_cast<const bf16x8*>(Pb + (size_t)u0 * HID + g * 8);
        const bf16x8 r1 = *reinterpret_cast<const bf16x8*>(Pb + (size_t)u1 * HID + g * 8);
#pragma unroll
        for (int j = 0; j < 8; ++j)
            acc[j] += bf2f((unsigned short)r0[j]) + bf2f((unsigned short)r1[j]);
    }
    if (e < hi) {
        const int u = src[e];
        const bf16x8 r = *reinterpret_cast<const bf16x8*>(Pb + (size_t)u * HID + g * 8);
#pragma unroll
        for (int j = 0; j < 8; ++j) acc[j] += bf2f((unsigned short)r[j]);
    }
#pragma unroll
    for (int j = 0; j < 8; ++j) {
        acc[j] += __shfl_xor(acc[j], 16);
        acc[j] += __shfl_xor(acc[j], 32);
    }

    if (q == 0) {
        const float4 b0 = *reinterpret_cast<const float4*>(bias + g * 8);
        const float4 b1 = *reinterpret_cast<const float4*>(bias + g * 8 + 4);
        float4 a = make_float4(fmaxf(acc[0] * inv + b0.x, 0.f), fmaxf(acc[1] * inv + b0.y, 0.f),
                               fmaxf(acc[2] * inv + b0.z, 0.f), fmaxf(acc[3] * inv + b0.w, 0.f));
        float4 b = make_float4(fmaxf(acc[4] * inv + b1.x, 0.f), fmaxf(acc[5] * inv + b1.y, 0.f),
                               fmaxf(acc[6] * inv + b1.z, 0.f), fmaxf(acc[7] * inv + b1.w, 0.f));
        *reinterpret_cast<float4*>(out + (size_t)v * HID + g * 8)     = a;
        *reinterpret_cast<float4*>(out + (size_t)v * HID + g * 8 + 4) = b;
    }
}

// ---------------------------------------------------------------------------
// Pool stage A: 1024 blocks (64 graphs x 16 splits) write UNSCALED partial
// sums to hgp[g*PSPLIT+s][128]. No atomics, no memset needed.
// ---------------------------------------------------------------------------
__global__ void pool_partial_kernel(const float* __restrict__ h3,
                                    const int* __restrict__ graph_ptr,
                                    float* __restrict__ hgp) {
    const int g   = blockIdx.x / PSPLIT;
    const int s   = blockIdx.x % PSPLIT;
    const int j   = threadIdx.x;                // 128
    const int lo  = graph_ptr[g];
    const int hi  = graph_ptr[g + 1];

    float acc = 0.f;
    for (int r = lo + s; r < hi; r += PSPLIT)
        acc += h3[(size_t)r * HID + j];
    hgp[(size_t)blockIdx.x * HID + j] = acc;
}

// ---------------------------------------------------------------------------
// Pool stage B + classifier: block per graph. Reduce 16 partials, scale,
// then 2-layer classifier (row-local).
// ---------------------------------------------------------------------------
__global__ void cls_kernel(const float* __restrict__ hgp,
                           const int* __restrict__ graph_ptr,
                           const float* __restrict__ Wc1,
                           const float* __restrict__ bc1,
                           const float* __restrict__ Wc2,
                           const float* __restrict__ bc2,
                           float* __restrict__ out) {
    const int g = blockIdx.x;                   // 64
    const int j = threadIdx.x;                  // 128
    const int cnt = graph_ptr[g + 1] - graph_ptr[g];
    const float inv = 1.0f / (float)max(cnt, 1);

    float acc = 0.f;
#pragma unroll
    for (int s = 0; s < PSPLIT; ++s)
        acc += hgp[(size_t)(g * PSPLIT + s) * HID + j];

    __shared__ float row[HID];
    __shared__ float trow[HID];
    row[j] = acc * inv;
    __syncthreads();

    float a1 = bc1[j];
#pragma unroll 4
    for (int k = 0; k < HID; ++k) a1 = fmaf(row[k], Wc1[k * HID + j], a1);
    trow[j] = fmaxf(a1, 0.f);
    __syncthreads();

    if (j < N_CLASSES) {
        float a2 = bc2[j];
#pragma unroll 4
        for (int k = 0; k < HID; ++k) a2 = fmaf(trow[k], Wc2[k * N_CLASSES + j], a2);
        out[g * N_CLASSES + j] = a2;
    }
}

// ---------------------------------------------------------------------------
extern "C" void kernel_launch(void* const* d_in, const int* in_sizes, int n_in,
                              void* d_out, int out_size, void* d_ws, size_t ws_size,
                              hipStream_t stream) {
    const float* nf   = (const float*)d_in[0];
    const int*   src  = (const int*)  d_in[1];
    const int*   dst  = (const int*)  d_in[2];
    const int*   gid  = (const int*)  d_in[3];
    const float* W1  = (const float*)d_in[5];
    const float* b1  = (const float*)d_in[6];
    const float* W2  = (const float*)d_in[7];
    const float* b2  = (const float*)d_in[8];
    const float* W3  = (const float*)d_in[9];
    const float* b3  = (const float*)d_in[10];
    const float* Wc1 = (const float*)d_in[11];
    const float* bc1 = (const float*)d_in[12];
    const float* Wc2 = (const float*)d_in[13];
    const float* bc2 = (const float*)d_in[14];
    float* out = (float*)d_out;

    char* ws = (char*)d_ws;
    size_t off = 0;
    auto alloc = [&](size_t bytes) { void* p = ws + off; off = (off + bytes + 255) & ~(size_t)255; return p; };
    int*   node_ptr  = (int*)  alloc((N_NODES + 1) * sizeof(int));
    int*   graph_ptr = (int*)  alloc((N_GRAPHS + 1) * sizeof(int));
    // region A: nfb (bf16 M x 96) dead after gemm1; reused for h3 (fp32 M x 128)
    char*  regionA   = (char*) alloc((size_t)N_NODES * HID * sizeof(float));
    unsigned short* nfb = (unsigned short*)regionA;
    float*          h3  = (float*)regionA;
    unsigned short* PbA = (unsigned short*)alloc((size_t)N_NODES * HID * sizeof(unsigned short));
    unsigned short* PbB = (unsigned short*)alloc((size_t)N_NODES * HID * sizeof(unsigned short));
    unsigned short* wt1 = (unsigned short*)alloc((size_t)HID * KP1 * sizeof(unsigned short));
    unsigned short* wt2 = (unsigned short*)alloc((size_t)HID * HID * sizeof(unsigned short));
    unsigned short* wt3 = (unsigned short*)alloc((size_t)HID * HID * sizeof(unsigned short));
    float* hgp       = (float*)alloc((size_t)N_GRAPHS * PSPLIT * HID * sizeof(float));
    (void)ws_size;

    const int GEMM_GRID = (N_NODES + 63) / 64;   // 782
    const int AGG_GRID  = (N_NODES + 3) / 4;

    // 1. fused prep
    prep_kernel<<<NB_CONV + NB_ROW + NB_WT, 256, 0, stream>>>(
        nf, dst, gid, W1, W2, W3, nfb, node_ptr, graph_ptr, wt1, wt2, wt3);

    // 2. P1 = nfb @ W1
    mfma_gemm_kernel<KP1><<<GEMM_GRID, 256, 0, stream>>>(nfb, wt1, PbA, N_NODES);

    // 3. h1 = relu(agg(P1)+b1); P2 = h1 @ W2
    fused_agg_gemm_kernel<<<GEMM_GRID, 256, 0, stream>>>(PbA, src, node_ptr, b1, wt2, PbB, N_NODES);

    // 4. h2 = relu(agg(P2)+b2); P3 = h2 @ W3
    fused_agg_gemm_kernel<<<GEMM_GRID, 256, 0, stream>>>(PbB, src, node_ptr, b2, wt3, PbA, N_NODES);

    // 5. h3 = relu(agg(P3)+b3)  (fp32)
    agg128_f32_kernel<<<AGG_GRID, 256, 0, stream>>>(PbA, src, node_ptr, b3, h3);

    // 6. pool partials (wide), 7. reduce + classifier
    pool_partial_kernel<<<N_GRAPHS * PSPLIT, HID, 0, stream>>>(h3, graph_ptr, hgp);
    cls_kernel<<<N_GRAPHS, HID, 0, stream>>>(hgp, graph_ptr, Wc1, bc1, Wc2, bc2, out);
}

// Round 8
// 179.649 us; speedup vs baseline: 1.3876x; 1.2028x over previous
//
#include <hip/hip_runtime.h>

#define N_NODES   50000
#define N_EDGES   800000
#define IN_DIM    89
#define KP1       96      // IN_DIM padded to multiple of 32
#define HID       128
#define N_CLASSES 64
#define N_GRAPHS  64
#define PSPLIT    16      // pool partial splits per graph

typedef __attribute__((ext_vector_type(8))) short bf16x8;
typedef __attribute__((ext_vector_type(4))) float f32x4;

__device__ __forceinline__ unsigned short f2bf(float x) {
    union { float f; unsigned u; } v; v.f = x;
    unsigned r = v.u + 0x7FFF + ((v.u >> 16) & 1);   // RTNE
    return (unsigned short)(r >> 16);
}
__device__ __forceinline__ float bf2f(unsigned short x) {
    union { unsigned u; float f; } v; v.u = ((unsigned)x) << 16;
    return v.f;
}

// ---------------------------------------------------------------------------
// Fused prep: conv_nf | rowptr | wt1/wt2/wt3 transpose+bf16, branched by block.
// ---------------------------------------------------------------------------
#define NB_CONV 18750                      // 50000*96/256
#define NB_ROW  196                        // ceil(50001/256)
#define NB_WT   176                        // ceil((128*96+2*128*128)/256)

__global__ void prep_kernel(const float* __restrict__ nf,
                            const int* __restrict__ dst,
                            const int* __restrict__ gid,
                            const float* __restrict__ W1,
                            const float* __restrict__ W2,
                            const float* __restrict__ W3,
                            unsigned short* __restrict__ nfb,
                            int* __restrict__ node_ptr,
                            int* __restrict__ graph_ptr,
                            unsigned short* __restrict__ wt1,
                            unsigned short* __restrict__ wt2,
                            unsigned short* __restrict__ wt3) {
    const int b = blockIdx.x;
    if (b < NB_CONV) {
        const int i = b * 256 + threadIdx.x;           // < 4.8M exactly
        const int row = i / KP1, k = i - row * KP1;
        nfb[i] = (k < IN_DIM) ? f2bf(nf[(size_t)row * IN_DIM + k]) : (unsigned short)0;
    } else if (b < NB_CONV + NB_ROW) {
        const int i = (b - NB_CONV) * 256 + threadIdx.x;
        if (i <= N_NODES) {
            int lo = 0, hi = N_EDGES;
            while (lo < hi) { int mid = (lo + hi) >> 1; if (dst[mid] < i) lo = mid + 1; else hi = mid; }
            node_ptr[i] = lo;
        }
        if (i <= N_GRAPHS) {
            int lo = 0, hi = N_NODES;
            while (lo < hi) { int mid = (lo + hi) >> 1; if (gid[mid] < i) lo = mid + 1; else hi = mid; }
            graph_ptr[i] = lo;
        }
    } else {
        int idx = (b - NB_CONV - NB_ROW) * 256 + threadIdx.x;
        if (idx < HID * KP1) {
            const int col = idx / KP1, k = idx - col * KP1;
            wt1[idx] = (k < IN_DIM) ? f2bf(W1[(size_t)k * HID + col]) : (unsigned short)0;
        } else if ((idx -= HID * KP1) < HID * HID) {
            const int col = idx / HID, k = idx - col * HID;
            wt2[idx] = f2bf(W2[(size_t)k * HID + col]);
        } else if ((idx -= HID * HID) < HID * HID) {
            const int col = idx / HID, k = idx - col * HID;
            wt3[idx] = f2bf(W3[(size_t)k * HID + col]);
        }
    }
}

// ---------------------------------------------------------------------------
// MFMA GEMM (layer 1 only): Y[M x 128](bf16) = Xb[M x KPAD](bf16) @ WT^T.
// Block = 4 waves; wave = 16 rows x 128 cols. No LDS.
// ---------------------------------------------------------------------------
template <int KPAD>
__global__ __launch_bounds__(256) void mfma_gemm_kernel(
        const unsigned short* __restrict__ Xb,
        const unsigned short* __restrict__ WT,
        unsigned short* __restrict__ Y, int M) {
    const int wave = threadIdx.x >> 6;
    const int lane = threadIdx.x & 63;
    const int r    = lane & 15;
    const int kg   = lane >> 4;

    const int row  = blockIdx.x * 64 + wave * 16 + r;
    const int rowc = (row < M) ? row : (M - 1);

    f32x4 acc[8];
#pragma unroll
    for (int i = 0; i < 8; ++i) acc[i] = (f32x4){0.f, 0.f, 0.f, 0.f};

    const unsigned short* xrow = Xb + (size_t)rowc * KPAD + kg * 8;

#pragma unroll
    for (int k0 = 0; k0 < KPAD; k0 += 32) {
        const bf16x8 a = *reinterpret_cast<const bf16x8*>(xrow + k0);
#pragma unroll
        for (int nf = 0; nf < 8; ++nf) {
            const bf16x8 b = *reinterpret_cast<const bf16x8*>(
                WT + (size_t)(nf * 16 + r) * KPAD + kg * 8 + k0);
            acc[nf] = __builtin_amdgcn_mfma_f32_16x16x32_bf16(a, b, acc[nf], 0, 0, 0);
        }
    }

    const int orow0 = blockIdx.x * 64 + wave * 16 + kg * 4;
#pragma unroll
    for (int nf = 0; nf < 8; ++nf)
#pragma unroll
        for (int q = 0; q < 4; ++q) {
            const int orow = orow0 + q;
            if (orow < M) Y[(size_t)orow * HID + nf * 16 + r] = f2bf(acc[nf][q]);
        }
}

// ---------------------------------------------------------------------------
// FUSED agg + GEMM:  h = relu(mean-agg(Pin) + bias);  Pout = h @ W (via WT).
// Block = 16 nodes, 4 waves. Phase 1: each wave aggregates 4 nodes into the
// shared 16x128 LDS tile. Phase 2 (after syncthreads): the 16x128 GEMM is
// column-split across waves — wave w computes cols [32w, 32w+32).
// Grid = 3125 blocks (50000 = 3125*16, exact) -> 12500 waves for the gather.
// ---------------------------------------------------------------------------
__global__ __launch_bounds__(256) void fused_agg_gemm_kernel(
        const unsigned short* __restrict__ Pin,
        const int* __restrict__ src,
        const int* __restrict__ node_ptr,
        const float* __restrict__ bias,
        const unsigned short* __restrict__ WT,
        unsigned short* __restrict__ Pout) {
    __shared__ unsigned short hs[16][136];      // 16 x 128 (+8 pad)

    const int wave = threadIdx.x >> 6;
    const int lane = threadIdx.x & 63;
    const int q    = lane >> 4;                 // edge sub-slot 0..3
    const int g    = lane & 15;                 // dim group [8g, 8g+8)
    const int vbase = blockIdx.x * 16;

    // ---- phase 1: each wave aggregates 4 nodes ----
    const float4 b0 = *reinterpret_cast<const float4*>(bias + g * 8);
    const float4 b1 = *reinterpret_cast<const float4*>(bias + g * 8 + 4);

#pragma unroll
    for (int i = 0; i < 4; ++i) {
        const int li = wave * 4 + i;            // local row 0..15
        const int v  = vbase + li;
        const int lo = node_ptr[v];
        const int hi = node_ptr[v + 1];
        const float inv = 1.0f / (float)max(hi - lo, 1);

        float acc[8];
#pragma unroll
        for (int j = 0; j < 8; ++j) acc[j] = 0.f;

        int e = lo + q;
        for (; e + 4 < hi; e += 8) {            // 2x unroll for MLP
            const int u0 = src[e];
            const int u1 = src[e + 4];
            const bf16x8 r0 = *reinterpret_cast<const bf16x8*>(Pin + (size_t)u0 * HID + g * 8);
            const bf16x8 r1 = *reinterpret_cast<const bf16x8*>(Pin + (size_t)u1 * HID + g * 8);
#pragma unroll
            for (int j = 0; j < 8; ++j)
                acc[j] += bf2f((unsigned short)r0[j]) + bf2f((unsigned short)r1[j]);
        }
        if (e < hi) {
            const int u = src[e];
            const bf16x8 r = *reinterpret_cast<const bf16x8*>(Pin + (size_t)u * HID + g * 8);
#pragma unroll
            for (int j = 0; j < 8; ++j) acc[j] += bf2f((unsigned short)r[j]);
        }
#pragma unroll
        for (int j = 0; j < 8; ++j) {
            acc[j] += __shfl_xor(acc[j], 16);
            acc[j] += __shfl_xor(acc[j], 32);
        }
        if (q == 0) {
            bf16x8 ob;
            ob[0] = (short)f2bf(fmaxf(acc[0] * inv + b0.x, 0.f));
            ob[1] = (short)f2bf(fmaxf(acc[1] * inv + b0.y, 0.f));
            ob[2] = (short)f2bf(fmaxf(acc[2] * inv + b0.z, 0.f));
            ob[3] = (short)f2bf(fmaxf(acc[3] * inv + b0.w, 0.f));
            ob[4] = (short)f2bf(fmaxf(acc[4] * inv + b1.x, 0.f));
            ob[5] = (short)f2bf(fmaxf(acc[5] * inv + b1.y, 0.f));
            ob[6] = (short)f2bf(fmaxf(acc[6] * inv + b1.z, 0.f));
            ob[7] = (short)f2bf(fmaxf(acc[7] * inv + b1.w, 0.f));
            *reinterpret_cast<bf16x8*>(&hs[li][g * 8]) = ob;
        }
    }
    __syncthreads();

    // ---- phase 2: GEMM 16x128, column-split: wave w -> nf {2w, 2w+1} ----
    const int r  = lane & 15;
    const int kg = lane >> 4;

    f32x4 acc2[2];
#pragma unroll
    for (int t = 0; t < 2; ++t) acc2[t] = (f32x4){0.f, 0.f, 0.f, 0.f};

#pragma unroll
    for (int k0 = 0; k0 < HID; k0 += 32) {
        const bf16x8 a = *reinterpret_cast<const bf16x8*>(&hs[r][kg * 8 + k0]);
#pragma unroll
        for (int t = 0; t < 2; ++t) {
            const int nf = wave * 2 + t;
            const bf16x8 b = *reinterpret_cast<const bf16x8*>(
                WT + (size_t)(nf * 16 + r) * HID + kg * 8 + k0);
            acc2[t] = __builtin_amdgcn_mfma_f32_16x16x32_bf16(a, b, acc2[t], 0, 0, 0);
        }
    }

    const int orow0 = vbase + kg * 4;
#pragma unroll
    for (int t = 0; t < 2; ++t) {
        const int nf = wave * 2 + t;
#pragma unroll
        for (int p = 0; p < 4; ++p)
            Pout[(size_t)(orow0 + p) * HID + nf * 16 + r] = f2bf(acc2[t][p]);
    }
}

// ---------------------------------------------------------------------------
// Final aggregation (layer 3): fp32 output for pooling.
// ---------------------------------------------------------------------------
__global__ void agg128_f32_kernel(const unsigned short* __restrict__ Pb,
                                  const int* __restrict__ src,
                                  const int* __restrict__ node_ptr,
                                  const float* __restrict__ bias,
                                  float* __restrict__ out) {
    const int wave = threadIdx.x >> 6;
    const int lane = threadIdx.x & 63;
    const int v    = blockIdx.x * 4 + wave;
    if (v >= N_NODES) return;

    const int lo = node_ptr[v];
    const int hi = node_ptr[v + 1];
    const float inv = 1.0f / (float)max(hi - lo, 1);

    const int q = lane >> 4;
    const int g = lane & 15;

    float acc[8];
#pragma unroll
    for (int j = 0; j < 8; ++j) acc[j] = 0.f;

    int e = lo + q;
    for (; e + 4 < hi; e += 8) {
        const int u0 = src[e];
        const int u1 = src[e + 4];
        const bf16x8 r0 = *reinterpret_cast<const bf16x8*>(Pb + (size_t)u0 * HID + g * 8);
        const bf16x8 r1 = *reinterpret_cast<const bf16x8*>(Pb + (size_t)u1 * HID + g * 8);
#pragma unroll
        for (int j = 0; j < 8; ++j)
            acc[j] += bf2f((unsigned short)r0[j]) + bf2f((unsigned short)r1[j]);
    }
    if (e < hi) {
        const int u = src[e];
        const bf16x8 r = *reinterpret_cast<const bf16x8*>(Pb + (size_t)u * HID + g * 8);
#pragma unroll
        for (int j = 0; j < 8; ++j) acc[j] += bf2f((unsigned short)r[j]);
    }
#pragma unroll
    for (int j = 0; j < 8; ++j) {
        acc[j] += __shfl_xor(acc[j], 16);
        acc[j] += __shfl_xor(acc[j], 32);
    }

    if (q == 0) {
        const float4 b0 = *reinterpret_cast<const float4*>(bias + g * 8);
        const float4 b1 = *reinterpret_cast<const float4*>(bias + g * 8 + 4);
        float4 a = make_float4(fmaxf(acc[0] * inv + b0.x, 0.f), fmaxf(acc[1] * inv + b0.y, 0.f),
                               fmaxf(acc[2] * inv + b0.z, 0.f), fmaxf(acc[3] * inv + b0.w, 0.f));
        float4 b = make_float4(fmaxf(acc[4] * inv + b1.x, 0.f), fmaxf(acc[5] * inv + b1.y, 0.f),
                               fmaxf(acc[6] * inv + b1.z, 0.f), fmaxf(acc[7] * inv + b1.w, 0.f));
        *reinterpret_cast<float4*>(out + (size_t)v * HID + g * 8)     = a;
        *reinterpret_cast<float4*>(out + (size_t)v * HID + g * 8 + 4) = b;
    }
}

// ---------------------------------------------------------------------------
// Pool stage A: 1024 blocks (64 graphs x 16 splits), unscaled partial sums.
// ---------------------------------------------------------------------------
__global__ void pool_partial_kernel(const float* __restrict__ h3,
                                    const int* __restrict__ graph_ptr,
                                    float* __restrict__ hgp) {
    const int g   = blockIdx.x / PSPLIT;
    const int s   = blockIdx.x % PSPLIT;
    const int j   = threadIdx.x;                // 128
    const int lo  = graph_ptr[g];
    const int hi  = graph_ptr[g + 1];

    float acc = 0.f;
    for (int r = lo + s; r < hi; r += PSPLIT)
        acc += h3[(size_t)r * HID + j];
    hgp[(size_t)blockIdx.x * HID + j] = acc;
}

// ---------------------------------------------------------------------------
// Pool stage B + classifier: block per graph.
// ---------------------------------------------------------------------------
__global__ void cls_kernel(const float* __restrict__ hgp,
                           const int* __restrict__ graph_ptr,
                           const float* __restrict__ Wc1,
                           const float* __restrict__ bc1,
                           const float* __restrict__ Wc2,
                           const float* __restrict__ bc2,
                           float* __restrict__ out) {
    const int g = blockIdx.x;                   // 64
    const int j = threadIdx.x;                  // 128
    const int cnt = graph_ptr[g + 1] - graph_ptr[g];
    const float inv = 1.0f / (float)max(cnt, 1);

    float acc = 0.f;
#pragma unroll
    for (int s = 0; s < PSPLIT; ++s)
        acc += hgp[(size_t)(g * PSPLIT + s) * HID + j];

    __shared__ float row[HID];
    __shared__ float trow[HID];
    row[j] = acc * inv;
    __syncthreads();

    float a1 = bc1[j];
#pragma unroll 4
    for (int k = 0; k < HID; ++k) a1 = fmaf(row[k], Wc1[k * HID + j], a1);
    trow[j] = fmaxf(a1, 0.f);
    __syncthreads();

    if (j < N_CLASSES) {
        float a2 = bc2[j];
#pragma unroll 4
        for (int k = 0; k < HID; ++k) a2 = fmaf(trow[k], Wc2[k * N_CLASSES + j], a2);
        out[g * N_CLASSES + j] = a2;
    }
}

// ---------------------------------------------------------------------------
extern "C" void kernel_launch(void* const* d_in, const int* in_sizes, int n_in,
                              void* d_out, int out_size, void* d_ws, size_t ws_size,
                              hipStream_t stream) {
    const float* nf   = (const float*)d_in[0];
    const int*   src  = (const int*)  d_in[1];
    const int*   dst  = (const int*)  d_in[2];
    const int*   gid  = (const int*)  d_in[3];
    const float* W1  = (const float*)d_in[5];
    const float* b1  = (const float*)d_in[6];
    const float* W2  = (const float*)d_in[7];
    const float* b2  = (const float*)d_in[8];
    const float* W3  = (const float*)d_in[9];
    const float* b3  = (const float*)d_in[10];
    const float* Wc1 = (const float*)d_in[11];
    const float* bc1 = (const float*)d_in[12];
    const float* Wc2 = (const float*)d_in[13];
    const float* bc2 = (const float*)d_in[14];
    float* out = (float*)d_out;

    char* ws = (char*)d_ws;
    size_t off = 0;
    auto alloc = [&](size_t bytes) { void* p = ws + off; off = (off + bytes + 255) & ~(size_t)255; return p; };
    int*   node_ptr  = (int*)  alloc((N_NODES + 1) * sizeof(int));
    int*   graph_ptr = (int*)  alloc((N_GRAPHS + 1) * sizeof(int));
    // region A: nfb (bf16 M x 96) dead after gemm1; reused for h3 (fp32 M x 128)
    char*  regionA   = (char*) alloc((size_t)N_NODES * HID * sizeof(float));
    unsigned short* nfb = (unsigned short*)regionA;
    float*          h3  = (float*)regionA;
    unsigned short* PbA = (unsigned short*)alloc((size_t)N_NODES * HID * sizeof(unsigned short));
    unsigned short* PbB = (unsigned short*)alloc((size_t)N_NODES * HID * sizeof(unsigned short));
    unsigned short* wt1 = (unsigned short*)alloc((size_t)HID * KP1 * sizeof(unsigned short));
    unsigned short* wt2 = (unsigned short*)alloc((size_t)HID * HID * sizeof(unsigned short));
    unsigned short* wt3 = (unsigned short*)alloc((size_t)HID * HID * sizeof(unsigned short));
    float* hgp       = (float*)alloc((size_t)N_GRAPHS * PSPLIT * HID * sizeof(float));
    (void)ws_size;

    const int GEMM_GRID  = (N_NODES + 63) / 64;   // 782
    const int FUSED_GRID = N_NODES / 16;          // 3125 (exact)
    const int AGG_GRID   = (N_NODES + 3) / 4;

    // 1. fused prep
    prep_kernel<<<NB_CONV + NB_ROW + NB_WT, 256, 0, stream>>>(
        nf, dst, gid, W1, W2, W3, nfb, node_ptr, graph_ptr, wt1, wt2, wt3);

    // 2. P1 = nfb @ W1
    mfma_gemm_kernel<KP1><<<GEMM_GRID, 256, 0, stream>>>(nfb, wt1, PbA, N_NODES);

    // 3. h1 = relu(agg(P1)+b1); P2 = h1 @ W2
    fused_agg_gemm_kernel<<<FUSED_GRID, 256, 0, stream>>>(PbA, src, node_ptr, b1, wt2, PbB);

    // 4. h2 = relu(agg(P2)+b2); P3 = h2 @ W3
    fused_agg_gemm_kernel<<<FUSED_GRID, 256, 0, stream>>>(PbB, src, node_ptr, b2, wt3, PbA);

    // 5. h3 = relu(agg(P3)+b3)  (fp32)
    agg128_f32_kernel<<<AGG_GRID, 256, 0, stream>>>(PbA, src, node_ptr, b3, h3);

    // 6. pool partials (wide), 7. reduce + classifier
    pool_partial_kernel<<<N_GRAPHS * PSPLIT, HID, 0, stream>>>(h3, graph_ptr, hgp);
    cls_kernel<<<N_GRAPHS, HID, 0, stream>>>(hgp, graph_ptr, Wc1, bc1, Wc2, bc2, out);
}